// Round 1
// baseline (950.345 us; speedup 1.0000x reference)
//
#include <hip/hip_runtime.h>
#include <math.h>

#define HDIM 128      // hidden width
#define PTS  64       // points per workgroup
#define TJ   32       // K-tile rows staged in LDS per GEMM step
#define NTHREADS 256

#define EMV      0.001f
#define LFIX     0.05f
#define KFIX     100.0f           // E0 * 100
#define LAMBDA_L 0.5769230769230769f   // E0*NU/((1+NU)(1-2NU))
#define MU_L     0.3846153846153846f   // E0/(2(1+NU))

// 64-lane wave reduction (threads 0..63 == wave 0)
__device__ __forceinline__ float wred(float v) {
#pragma unroll
    for (int off = 32; off > 0; off >>= 1) v += __shfl_down(v, off, 64);
    return v;
}

// partial sum-of-squares of an LDS [HDIM][PTS] buffer: npart[c*PTS+p] = sum over k in c-th quarter
__device__ __forceinline__ void norm_partial(const float* buf, float* npart, int tid) {
    int p = tid & 63, c = tid >> 6;
    float a = 0.f;
    int k0 = c * 32;
#pragma unroll 8
    for (int k = k0; k < k0 + 32; ++k) { float v = buf[k * PTS + p]; a += v * v; }
    npart[c * PTS + p] = a;
}

// Register-tiled GEMM on LDS-resident activations.
// Activations stored transposed: a[j*PTS + p].
// !TRANSB: out[p][k] = sum_j a[p][j] * W[j][k]      (forward / tangent)
//  TRANSB: out[p][j] = sum_k a[p][k] * W[j][k]      (backward, W^T)
// MODE 0: out = tanh(z + bias[k]); MODE 1: out = z * (1 - h[k][p]^2) (h = hsc buffer)
// In-place (outb == a) is safe: all writes happen after the final internal barrier.
template <int MODE, bool TRANSB>
__device__ __forceinline__ void gemm_hp(const float* __restrict__ Wg,
                                        const float* a, float* outb, float* Wts,
                                        const float* __restrict__ bias,
                                        const float* hsc, int tid) {
    const int pg = tid & 15, cg = tid >> 4;
    const int p0 = pg * 4, k0 = cg * 8;
    float acc[4][8];
#pragma unroll
    for (int i = 0; i < 4; ++i)
#pragma unroll
        for (int j = 0; j < 8; ++j) acc[i][j] = 0.f;

    for (int t = 0; t < HDIM / TJ; ++t) {
        if (!TRANSB) {
            // stage rows t*TJ..t*TJ+31 of W (row-major) straight into Wts[jl][k]
            const float4* src = (const float4*)(Wg + t * TJ * HDIM);
            float4* dst = (float4*)Wts;
#pragma unroll
            for (int v = 0; v < (TJ * HDIM / 4) / NTHREADS; ++v)
                dst[tid + v * NTHREADS] = src[tid + v * NTHREADS];
        } else {
            // stage columns t*TJ..+31 of W, transposed: Wts[kl][j] = W[j][t*TJ+kl]
#pragma unroll
            for (int v = 0; v < (TJ * HDIM / 4) / NTHREADS; ++v) {
                int f = tid + v * NTHREADS;      // float4 index over (j, kl4)
                int j = f >> 3, kl4 = f & 7;
                float4 w = *(const float4*)(Wg + j * HDIM + t * TJ + kl4 * 4);
                Wts[(kl4 * 4 + 0) * HDIM + j] = w.x;
                Wts[(kl4 * 4 + 1) * HDIM + j] = w.y;
                Wts[(kl4 * 4 + 2) * HDIM + j] = w.z;
                Wts[(kl4 * 4 + 3) * HDIM + j] = w.w;
            }
        }
        __syncthreads();
#pragma unroll 8
        for (int jl = 0; jl < TJ; ++jl) {
            float4 av = *(const float4*)(a + (t * TJ + jl) * PTS + p0);
            float4 w0 = *(const float4*)(Wts + jl * HDIM + k0);
            float4 w1 = *(const float4*)(Wts + jl * HDIM + k0 + 4);
            float avv[4] = {av.x, av.y, av.z, av.w};
            float wv[8] = {w0.x, w0.y, w0.z, w0.w, w1.x, w1.y, w1.z, w1.w};
#pragma unroll
            for (int pi = 0; pi < 4; ++pi)
#pragma unroll
                for (int ki = 0; ki < 8; ++ki) acc[pi][ki] += avv[pi] * wv[ki];
        }
        __syncthreads();
    }
    // epilogue (after final barrier -> in-place safe)
#pragma unroll
    for (int ki = 0; ki < 8; ++ki) {
        int k = k0 + ki;
        float b = (MODE == 0) ? bias[k] : 0.f;
        float r[4];
#pragma unroll
        for (int pi = 0; pi < 4; ++pi) {
            float z = acc[pi][ki];
            if (MODE == 0) {
                r[pi] = tanhf(z + b);
            } else {
                float hv = hsc[k * PTS + p0 + pi];
                r[pi] = z * (1.f - hv * hv);
            }
        }
        float4 res = {r[0], r[1], r[2], r[3]};
        *(float4*)(outb + k * PTS + p0) = res;
    }
}

__global__ void __launch_bounds__(NTHREADS) pinn_main(
    const float* __restrict__ xPhys, const float* __restrict__ coord,
    const float* __restrict__ W1, const float* __restrict__ b1,
    const float* __restrict__ W2, const float* __restrict__ b2,
    const float* __restrict__ W3, const float* __restrict__ b3,
    const float* __restrict__ W4, const float* __restrict__ b4,
    const int* __restrict__ nfixp,
    float* __restrict__ energy_c_out, float* __restrict__ u_out,
    float* __restrict__ acc) {
    __shared__ __align__(16) float h1s[HDIM * PTS];
    __shared__ __align__(16) float h2s[HDIM * PTS];
    __shared__ __align__(16) float h3s[HDIM * PTS];
    __shared__ __align__(16) float ts[HDIM * PTS];
    __shared__ __align__(16) float Wts[TJ * HDIM];
    __shared__ __align__(16) float xss[PTS * 4];
    __shared__ float xp3s[PTS], nxs[PTS], nh1s[PTS], nh2s[PTS], nh3s[PTS], ss[PTS];
    __shared__ float npart[12 * PTS];
    __shared__ float gls[PTS * 9];
    __shared__ float uls[PTS * 3];

    const int tid = threadIdx.x;
    const int base = blockIdx.x * PTS;
    const int nfixv = nfixp[0];

    if (tid < 3 * PTS) xss[(tid / 3) * 4 + (tid % 3)] = coord[base * 3 + tid];
    if (tid < PTS) {
        float xp = xPhys[base + tid];
        xp3s[tid] = xp * xp * xp;
        ss[tid] = 0.f;
    }
    __syncthreads();

    // ---- layer 1: h1[j][p] = tanh(b1[j] + sum_i x[p][i] W1[i][j])
    for (int v = 0; v < HDIM * PTS / NTHREADS; ++v) {
        int e = tid + v * NTHREADS;
        int j = e >> 6, p = e & 63;
        float z = b1[j] + xss[p * 4 + 0] * W1[j] + xss[p * 4 + 1] * W1[HDIM + j] +
                  xss[p * 4 + 2] * W1[2 * HDIM + j];
        h1s[j * PTS + p] = tanhf(z);
    }
    __syncthreads();
    gemm_hp<0, false>(W2, h1s, h2s, Wts, b2, nullptr, tid);
    __syncthreads();
    gemm_hp<0, false>(W3, h2s, h3s, Wts, b3, nullptr, tid);
    __syncthreads();

    // ---- u = h3 @ W4 + b4 ; write output
    if (tid < 3 * PTS) {
        int p = tid & 63, o = tid >> 6;
        float s = b4[o];
#pragma unroll 8
        for (int k = 0; k < HDIM; ++k) s += h3s[k * PTS + p] * W4[k * 3 + o];
        uls[p * 3 + o] = s;
        u_out[(base + p) * 3 + o] = s;
    }
    // ---- per-point squared norms of h1,h2,h3 (needed by trace)
    {
        int p = tid & 63, c = tid >> 6;
        float a1 = 0, a2 = 0, a3 = 0;
        int k0 = c * 32;
#pragma unroll 8
        for (int k = k0; k < k0 + 32; ++k) {
            float v1 = h1s[k * PTS + p], v2 = h2s[k * PTS + p], v3 = h3s[k * PTS + p];
            a1 += v1 * v1; a2 += v2 * v2; a3 += v3 * v3;
        }
        npart[(0 + c) * PTS + p] = a1;
        npart[(4 + c) * PTS + p] = a2;
        npart[(8 + c) * PTS + p] = a3;
    }
    __syncthreads();
    if (tid < PTS) {
        int p = tid;
        nh1s[p] = npart[0 * PTS + p] + npart[1 * PTS + p] + npart[2 * PTS + p] + npart[3 * PTS + p];
        nh2s[p] = npart[4 * PTS + p] + npart[5 * PTS + p] + npart[6 * PTS + p] + npart[7 * PTS + p];
        nh3s[p] = npart[8 * PTS + p] + npart[9 * PTS + p] + npart[10 * PTS + p] + npart[11 * PTS + p];
        float x0 = xss[p * 4], x1 = xss[p * 4 + 1], x2 = xss[p * 4 + 2];
        nxs[p] = x0 * x0 + x1 * x1 + x2 * x2;
        // E_fix contribution (only first n_fix points; mask = (clip(x0/L,0,1)==0))
        float sc = fminf(fmaxf(x0 * (1.0f / LFIX), 0.f), 1.f);
        float ef = 0.f;
        if ((base + p) < nfixv && sc == 0.f) {
            float u0 = uls[p * 3], u1 = uls[p * 3 + 1], u2 = uls[p * 3 + 2];
            ef = xp3s[p] * 0.5f * KFIX * (u0 * u0 + u1 * u1 + u2 * u2);
        }
        ef = wred(ef);
        if (tid == 0) atomicAdd(acc + 1, ef);
    }

    // ---- 3 forward-mode tangent passes (input directions e_i) -> g[i][o] = du_o/dc_i
    for (int i = 0; i < 3; ++i) {
        __syncthreads();
        for (int v = 0; v < HDIM * PTS / NTHREADS; ++v) {
            int e = tid + v * NTHREADS;
            int j = e >> 6, p = e & 63;
            float hv = h1s[j * PTS + p];
            ts[j * PTS + p] = (1.f - hv * hv) * W1[i * HDIM + j];
        }
        __syncthreads();
        gemm_hp<1, false>(W2, ts, ts, Wts, nullptr, h2s, tid);
        __syncthreads();
        gemm_hp<1, false>(W3, ts, ts, Wts, nullptr, h3s, tid);
        __syncthreads();
        if (tid < 3 * PTS) {
            int p = tid & 63, o = tid >> 6;
            float s = 0.f;
#pragma unroll 8
            for (int k = 0; k < HDIM; ++k) s += ts[k * PTS + p] * W4[k * 3 + o];
            gls[p * 9 + i * 3 + o] = s;
        }
    }
    __syncthreads();

    // ---- strain energy per point; write energy_c; accumulate mean(energy*xp^3)
    if (tid < PTS) {
        int p = tid;
        float g00 = gls[p * 9 + 0], g01 = gls[p * 9 + 1], g02 = gls[p * 9 + 2];
        float g10 = gls[p * 9 + 3], g11 = gls[p * 9 + 4], g12 = gls[p * 9 + 5];
        float g20 = gls[p * 9 + 6], g21 = gls[p * 9 + 7], g22 = gls[p * 9 + 8];
        float e11 = g11, e22 = g00, e33 = g22;
        float e12 = 0.5f * (g01 + g10);
        float e13 = 0.5f * (g21 + g12);
        float e23 = 0.5f * (g20 + g02);
        float tr = e11 + e22 + e33;
        float en = 0.5f * LAMBDA_L * tr * tr +
                   MU_L * (e11 * e11 + e22 * e22 + e33 * e33 +
                           2.f * (e12 * e12 + e13 * e13 + e23 * e23));
        float exp3 = en * xp3s[p];
        energy_c_out[base + p] = 2.f * exp3;
        float er = wred(exp3);
        if (tid == 0) atomicAdd(acc + 0, er);
    }

    // ---- exact parameter-Jacobian trace (replaces Hutchinson expectation)
    for (int o = 0; o < 3; ++o) {
        __syncthreads();
        for (int v = 0; v < HDIM * PTS / NTHREADS; ++v) {
            int e = tid + v * NTHREADS;
            int k = e >> 6, p = e & 63;
            float hv = h3s[k * PTS + p];
            ts[k * PTS + p] = (1.f - hv * hv) * W4[k * 3 + o];   // delta3
        }
        __syncthreads();
        norm_partial(ts, npart, tid);
        __syncthreads();
        if (tid < PTS)
            ss[tid] += (npart[tid] + npart[PTS + tid] + npart[2 * PTS + tid] + npart[3 * PTS + tid]) *
                       (1.f + nh2s[tid]);
        __syncthreads();
        gemm_hp<1, true>(W3, ts, ts, Wts, nullptr, h2s, tid);    // delta2
        __syncthreads();
        norm_partial(ts, npart, tid);
        __syncthreads();
        if (tid < PTS)
            ss[tid] += (npart[tid] + npart[PTS + tid] + npart[2 * PTS + tid] + npart[3 * PTS + tid]) *
                       (1.f + nh1s[tid]);
        __syncthreads();
        gemm_hp<1, true>(W2, ts, ts, Wts, nullptr, h1s, tid);    // delta1
        __syncthreads();
        norm_partial(ts, npart, tid);
        __syncthreads();
        if (tid < PTS)
            ss[tid] += (npart[tid] + npart[PTS + tid] + npart[2 * PTS + tid] + npart[3 * PTS + tid]) *
                       (1.f + nxs[tid]);
    }
    __syncthreads();
    if (tid < PTS) {
        int p = tid;
        float s = ss[p] + 3.f * (nh3s[p] + 1.f);   // W4/b4 terms, one per output o
        bool uu = (base + p) < nfixv;
        float su = uu ? s : 0.f;
        float sr = uu ? 0.f : s;
        su = wred(su);
        sr = wred(sr);
        if (tid == 0) { atomicAdd(acc + 3, su); atomicAdd(acc + 4, sr); }
    }
}

__global__ void __launch_bounds__(NTHREADS) pinn_force(
    const float* __restrict__ fc,
    const float* __restrict__ W1, const float* __restrict__ b1,
    const float* __restrict__ W2, const float* __restrict__ b2,
    const float* __restrict__ W3, const float* __restrict__ b3,
    const float* __restrict__ W4, const float* __restrict__ b4,
    const float* __restrict__ Fv, float* __restrict__ acc) {
    __shared__ __align__(16) float hs[HDIM * PTS];
    __shared__ __align__(16) float Wts[TJ * HDIM];
    __shared__ __align__(16) float xss[PTS * 4];
    __shared__ float uls[PTS * 3];

    const int tid = threadIdx.x;
    const int base = blockIdx.x * PTS;

    if (tid < 3 * PTS) xss[(tid / 3) * 4 + (tid % 3)] = fc[base * 3 + tid];
    __syncthreads();
    for (int v = 0; v < HDIM * PTS / NTHREADS; ++v) {
        int e = tid + v * NTHREADS;
        int j = e >> 6, p = e & 63;
        float z = b1[j] + xss[p * 4 + 0] * W1[j] + xss[p * 4 + 1] * W1[HDIM + j] +
                  xss[p * 4 + 2] * W1[2 * HDIM + j];
        hs[j * PTS + p] = tanhf(z);
    }
    __syncthreads();
    gemm_hp<0, false>(W2, hs, hs, Wts, b2, nullptr, tid);   // in-place safe
    __syncthreads();
    gemm_hp<0, false>(W3, hs, hs, Wts, b3, nullptr, tid);
    __syncthreads();
    if (tid < 3 * PTS) {
        int p = tid & 63, o = tid >> 6;
        float s = b4[o];
#pragma unroll 8
        for (int k = 0; k < HDIM; ++k) s += hs[k * PTS + p] * W4[k * 3 + o];
        uls[p * 3 + o] = s;
    }
    __syncthreads();
    if (tid < PTS) {
        float fsum = uls[tid * 3] * Fv[0] + uls[tid * 3 + 1] * Fv[1] + uls[tid * 3 + 2] * Fv[2];
        fsum = wred(fsum);
        if (tid == 0) atomicAdd(acc + 2, fsum);
    }
}

__global__ void pinn_final(const float* __restrict__ acc, float* __restrict__ out, int Ntot) {
    float es = acc[0], ef = acc[1], fl = acc[2], tu = acc[3], tr = acc[4];
    float energy_ans = EMV * (es / (float)Ntot);
    // E_fix = mean(ef_all[:nfix]) * (nfix/N) * EMV = ef_sum * EMV / N
    float E_fix = ef * EMV / (float)Ntot;
    float lam = tr / (tu + 1e-12f);
    lam = fminf(fmaxf(lam, 0.001f), 1000.f);
    out[0] = energy_ans - fl + lam * E_fix;
}

extern "C" void kernel_launch(void* const* d_in, const int* in_sizes, int n_in,
                              void* d_out, int out_size, void* d_ws, size_t ws_size,
                              hipStream_t stream) {
    const float* xPhys = (const float*)d_in[0];
    const float* coord = (const float*)d_in[1];
    const float* W1 = (const float*)d_in[2];
    const float* b1 = (const float*)d_in[3];
    const float* W2 = (const float*)d_in[4];
    const float* b2 = (const float*)d_in[5];
    const float* W3 = (const float*)d_in[6];
    const float* b3 = (const float*)d_in[7];
    const float* W4 = (const float*)d_in[8];
    const float* b4 = (const float*)d_in[9];
    const float* fc = (const float*)d_in[10];
    const float* Fv = (const float*)d_in[11];
    const int* nfix = (const int*)d_in[12];

    const int N = in_sizes[0];          // 65536
    const int NF = in_sizes[10] / 3;    // 4096
    float* out = (float*)d_out;
    float* acc = (float*)d_ws;          // [energy_sum, efix_sum, force_sum, tr_uu, tr_rr]

    hipMemsetAsync(acc, 0, 8 * sizeof(float), stream);
    pinn_main<<<dim3(N / PTS), dim3(NTHREADS), 0, stream>>>(
        xPhys, coord, W1, b1, W2, b2, W3, b3, W4, b4, nfix, out + 1, out + 1 + N, acc);
    pinn_force<<<dim3(NF / PTS), dim3(NTHREADS), 0, stream>>>(
        fc, W1, b1, W2, b2, W3, b3, W4, b4, Fv, acc);
    pinn_final<<<dim3(1), dim3(1), 0, stream>>>(acc, out, N);
}

// Round 2
// 193.915 us; speedup vs baseline: 4.9008x; 4.9008x over previous
//
#include <hip/hip_runtime.h>
#include <math.h>

typedef __bf16 bf16x8 __attribute__((ext_vector_type(8)));
typedef __bf16 bf16x4 __attribute__((ext_vector_type(4)));
typedef float f32x4 __attribute__((ext_vector_type(4)));

#define HDIM 128
#define PTS 64
#define NTHREADS 256

#define EMV 0.001f
#define LFIX 0.05f
#define KFIX 100.0f
#define LAMBDA_L 0.5769230769230769f
#define MU_L 0.3846153846153846f

// swizzled bf16-unit index of 16B block `blk` (0..15) in row r (rows of 128 bf16)
__device__ __forceinline__ int swb(int r, int blk) {
    return (r << 7) + ((blk ^ (r & 7)) << 3);
}

__device__ __forceinline__ float fast_tanh(float x) {
    float xc = fminf(fmaxf(x, -10.f), 10.f);
    float e = __expf(2.f * xc);
    return (e - 1.f) / (e + 1.f);
}

__device__ __forceinline__ float wred(float v) {
#pragma unroll
    for (int off = 32; off > 0; off >>= 1) v += __shfl_down(v, off, 64);
    return v;
}

// Wl[n][j] = Wg[j][n]  (transposed), bf16, swizzled.  For forward GEMMs (A = W^T).
__device__ __forceinline__ void stage_wt(const float* __restrict__ Wg, __bf16* Wl, int tid) {
    const int n = tid & 127;
    const int j0base = (tid >> 7) * 64;
#pragma unroll
    for (int jj = 0; jj < 64; jj += 4) {
        int j0 = j0base + jj;
        float a = Wg[(j0 + 0) * HDIM + n];
        float b = Wg[(j0 + 1) * HDIM + n];
        float c = Wg[(j0 + 2) * HDIM + n];
        float d = Wg[(j0 + 3) * HDIM + n];
        bf16x4 pk = {(__bf16)a, (__bf16)b, (__bf16)c, (__bf16)d};
        *(bf16x4*)(Wl + swb(n, j0 >> 3) + (j0 & 7)) = pk;
    }
}

// Wl[j][k] = Wg[j][k]  (row-major), bf16, swizzled.  For backward GEMMs (A = W).
__device__ __forceinline__ void stage_w(const float* __restrict__ Wg, __bf16* Wl, int tid) {
#pragma unroll
    for (int it = 0; it < 8; ++it) {
        int f = tid + it * NTHREADS;  // 2048 blocks of 8 elems
        int j = f >> 4, blk = f & 15;
        const float4* src = (const float4*)(Wg + j * HDIM + blk * 8);
        float4 v0 = src[0], v1 = src[1];
        bf16x8 pk = {(__bf16)v0.x, (__bf16)v0.y, (__bf16)v0.z, (__bf16)v0.w,
                     (__bf16)v1.x, (__bf16)v1.y, (__bf16)v1.z, (__bf16)v1.w};
        *(bf16x8*)(Wl + swb(j, blk)) = pk;
    }
}

// Batched MFMA GEMM: out[b][p][n] = sum_k A[n][k] * in[b][p][k], NB buffers share A.
// A = Wl (LDS, 128x128 bf16 swizzled).  D tile: row=n (from A), col=p (from B).
// EPI 0: buf0 -> tanh(acc+bias) (bf16 out), bufs 1.. -> acc * (1-h^2) with h the
//        locally computed fp32 tanh (no bf16 round-trip on the factor).
// EPI 1: all bufs -> acc * (1 - href[p][n]^2), href read from LDS.
// In-place safe: internal barrier between reads and writes.
template <int NB, int EPI>
__device__ __forceinline__ void mfma_block(const __bf16* __restrict__ Wl,
                                           __bf16* const* inb, __bf16* const* outb,
                                           const float* __restrict__ biasg,
                                           const __bf16* __restrict__ href, int tid) {
    const int lane = tid & 63;
    const int wid = tid >> 6;
    const int l15 = lane & 15;
    const int q = lane >> 4;
    const int rt0 = wid * 2;  // this wave's two row-tiles (n-dim), cols = all 4 p-tiles
    f32x4 acc[NB][2][4];
#pragma unroll
    for (int b = 0; b < NB; ++b)
#pragma unroll
        for (int r = 0; r < 2; ++r)
#pragma unroll
            for (int c = 0; c < 4; ++c) acc[b][r][c] = (f32x4){0.f, 0.f, 0.f, 0.f};

#pragma unroll
    for (int ks = 0; ks < 4; ++ks) {
        const int kb = ks * 4 + q;  // logical 8-elem block of this lane's k-range
        bf16x8 afr[2];
#pragma unroll
        for (int r = 0; r < 2; ++r)
            afr[r] = *(const bf16x8*)(Wl + swb((rt0 + r) * 16 + l15, kb));
#pragma unroll
        for (int b = 0; b < NB; ++b) {
            bf16x8 bfr[4];
#pragma unroll
            for (int c = 0; c < 4; ++c)
                bfr[c] = *(const bf16x8*)(inb[b] + swb(c * 16 + l15, kb));
#pragma unroll
            for (int r = 0; r < 2; ++r)
#pragma unroll
                for (int c = 0; c < 4; ++c)
                    acc[b][r][c] = __builtin_amdgcn_mfma_f32_16x16x32_bf16(
                        afr[r], bfr[c], acc[b][r][c], 0, 0, 0);
        }
    }
    __syncthreads();  // all B reads complete before in-place writes
#pragma unroll
    for (int r = 0; r < 2; ++r) {
        const int n0 = (rt0 + r) * 16 + q * 4;  // 4 consecutive output channels
        float bias4[4];
        if (EPI == 0) {
            float4 bv = *(const float4*)(biasg + n0);
            bias4[0] = bv.x; bias4[1] = bv.y; bias4[2] = bv.z; bias4[3] = bv.w;
        }
#pragma unroll
        for (int c = 0; c < 4; ++c) {
            const int p = c * 16 + l15;
            const int widx = swb(p, n0 >> 3) + (n0 & 7);
            float fct[4];
            if (EPI == 0) {
                bf16x4 hv;
#pragma unroll
                for (int i = 0; i < 4; ++i) {
                    float h = fast_tanh(acc[0][r][c][i] + bias4[i]);
                    hv[i] = (__bf16)h;
                    fct[i] = 1.f - h * h;
                }
                *(bf16x4*)(outb[0] + widx) = hv;
            } else {
                bf16x4 hv = *(const bf16x4*)(href + widx);
#pragma unroll
                for (int i = 0; i < 4; ++i) {
                    float h = (float)hv[i];
                    fct[i] = 1.f - h * h;
                }
            }
            const int bstart = (EPI == 0) ? 1 : 0;
#pragma unroll
            for (int b = bstart; b < NB; ++b) {
                bf16x4 ov;
#pragma unroll
                for (int i = 0; i < 4; ++i) ov[i] = (__bf16)(acc[b][r][c][i] * fct[i]);
                *(bf16x4*)(outb[b] + widx) = ov;
            }
        }
    }
}

// per-(p) partial sum-of-squares of three bf16 buffers -> npart[12][64]
__device__ __forceinline__ void dnorms(const __bf16* a, const __bf16* b, const __bf16* c2,
                                       float* npart, int tid) {
    int p = tid & 63, cc = tid >> 6;
    float s0 = 0.f, s1 = 0.f, s2 = 0.f;
#pragma unroll
    for (int blk = cc * 4; blk < cc * 4 + 4; ++blk) {
        bf16x8 v0 = *(const bf16x8*)(a + swb(p, blk));
        bf16x8 v1 = *(const bf16x8*)(b + swb(p, blk));
        bf16x8 v2 = *(const bf16x8*)(c2 + swb(p, blk));
#pragma unroll
        for (int e = 0; e < 8; ++e) {
            float f0 = (float)v0[e], f1 = (float)v1[e], f2 = (float)v2[e];
            s0 += f0 * f0; s1 += f1 * f1; s2 += f2 * f2;
        }
    }
    npart[(0 + cc) * PTS + p] = s0;
    npart[(4 + cc) * PTS + p] = s1;
    npart[(8 + cc) * PTS + p] = s2;
}

__device__ __forceinline__ float sum12(const float* npart, int p) {
    float d = 0.f;
#pragma unroll
    for (int i = 0; i < 12; ++i) d += npart[i * PTS + p];
    return d;
}

__global__ void __launch_bounds__(NTHREADS) pinn_all(
    const float* __restrict__ xPhys, const float* __restrict__ coord,
    const float* __restrict__ W1, const float* __restrict__ b1,
    const float* __restrict__ W2, const float* __restrict__ b2,
    const float* __restrict__ W3, const float* __restrict__ b3,
    const float* __restrict__ W4, const float* __restrict__ b4,
    const float* __restrict__ fc, const float* __restrict__ Fv,
    const int* __restrict__ nfixp,
    float* __restrict__ energy_c_out, float* __restrict__ u_out,
    float* __restrict__ acc, int nmain) {
    __shared__ __align__(16) __bf16 Wstage[HDIM * HDIM];
    __shared__ __align__(16) __bf16 h1s[PTS * HDIM], h2s[PTS * HDIM], h3s[PTS * HDIM];
    __shared__ __align__(16) __bf16 t0s[PTS * HDIM], t1s[PTS * HDIM], t2s[PTS * HDIM];
    __shared__ __align__(16) __bf16 W4p[16 * HDIM];   // padded W4^T (rows 3..15 zero)
    __shared__ __align__(16) float W4ts[3 * HDIM];    // W4^T fp32
    __shared__ __align__(16) float xss[PTS * 4];
    __shared__ float xp3s[PTS], nh1s[PTS], nh2s[PTS], nh3s[PTS], nxs[PTS], sss[PTS];
    __shared__ float npart[12 * PTS];
    __shared__ float gls[PTS * 12];
    __shared__ float uls[PTS * 4];

    const int tid = threadIdx.x;
    const int lane = tid & 63, wid = tid >> 6, l15 = lane & 15, q = lane >> 4;

    if ((int)blockIdx.x < nmain) {
        // ================= main path: 64 coord points =================
        const int base = blockIdx.x * PTS;
        const int nfixv = nfixp[0];

        if (tid < 3 * PTS) xss[(tid / 3) * 4 + (tid % 3)] = coord[base * 3 + tid];
        if (tid < PTS) {
            float xp = xPhys[base + tid];
            xp3s[tid] = xp * xp * xp;
            sss[tid] = 0.f;
        }
        for (int e = tid; e < 16 * HDIM; e += NTHREADS) {
            int o = e >> 7, k = e & 127;
            float v = (o < 3) ? W4[k * 3 + o] : 0.f;
            W4p[swb(o, k >> 3) + (k & 7)] = (__bf16)v;
            if (o < 3) W4ts[o * HDIM + k] = v;
        }
        __syncthreads();

        // layer 1 (fp32) -> h1 bf16; tangent seeds t_i = (1-h^2)*W1[i] (fp32 factor)
#pragma unroll
        for (int it = 0; it < 4; ++it) {
            int f = tid + it * NTHREADS;
            int p = f >> 4, blk = f & 15, j0 = blk * 8;
            float x0 = xss[p * 4], x1 = xss[p * 4 + 1], x2 = xss[p * 4 + 2];
            bf16x8 hv, t0v, t1v, t2v;
#pragma unroll
            for (int jj = 0; jj < 8; ++jj) {
                int j = j0 + jj;
                float w0 = W1[j], w1 = W1[HDIM + j], w2 = W1[2 * HDIM + j];
                float z = b1[j] + x0 * w0 + x1 * w1 + x2 * w2;
                float h = fast_tanh(z);
                float fct = 1.f - h * h;
                hv[jj] = (__bf16)h;
                t0v[jj] = (__bf16)(fct * w0);
                t1v[jj] = (__bf16)(fct * w1);
                t2v[jj] = (__bf16)(fct * w2);
            }
            int wi = swb(p, blk);
            *(bf16x8*)(h1s + wi) = hv;
            *(bf16x8*)(t0s + wi) = t0v;
            *(bf16x8*)(t1s + wi) = t1v;
            *(bf16x8*)(t2s + wi) = t2v;
        }
        stage_wt(W2, Wstage, tid);
        __syncthreads();

        {  // layer 2: forward + 3 tangents, shared weight fragments
            __bf16* ib[4] = {h1s, t0s, t1s, t2s};
            __bf16* ob[4] = {h2s, t0s, t1s, t2s};
            mfma_block<4, 0>(Wstage, ib, ob, b2, nullptr, tid);
        }
        __syncthreads();
        stage_wt(W3, Wstage, tid);
        __syncthreads();
        {  // layer 3
            __bf16* ib[4] = {h2s, t0s, t1s, t2s};
            __bf16* ob[4] = {h3s, t0s, t1s, t2s};
            mfma_block<4, 0>(Wstage, ib, ob, b3, nullptr, tid);
        }
        __syncthreads();

        {  // head: u = h3@W4+b4 and J columns g[i][o] = t_i@W4, via padded-W4 MFMA
            __bf16* bl[4] = {h3s, t0s, t1s, t2s};
            f32x4 ha[4];
#pragma unroll
            for (int b = 0; b < 4; ++b) ha[b] = (f32x4){0.f, 0.f, 0.f, 0.f};
#pragma unroll
            for (int ks = 0; ks < 4; ++ks) {
                int kb = ks * 4 + q;
                bf16x8 af = *(const bf16x8*)(W4p + swb(l15, kb));
#pragma unroll
                for (int b = 0; b < 4; ++b) {
                    bf16x8 bf_ = *(const bf16x8*)(bl[b] + swb(wid * 16 + l15, kb));
                    ha[b] = __builtin_amdgcn_mfma_f32_16x16x32_bf16(af, bf_, ha[b], 0, 0, 0);
                }
            }
            if (q == 0) {  // rows 0..3 of D -> outputs o=0..2
                int p = wid * 16 + l15;
#pragma unroll
                for (int o = 0; o < 3; ++o) {
                    float uv = ha[0][o] + b4[o];
                    uls[p * 4 + o] = uv;
                    u_out[(base + p) * 3 + o] = uv;
                }
#pragma unroll
                for (int b = 1; b < 4; ++b)
#pragma unroll
                    for (int o = 0; o < 3; ++o) gls[p * 12 + (b - 1) * 3 + o] = ha[b][o];
            }
        }
        __syncthreads();

        // norms of h1,h2,h3 ; trace seeds d3_o = (1-h3^2)*W4t[o] ; stage W3 row-major
        {
            int p = tid & 63, cc = tid >> 6;
            float a1 = 0.f, a2 = 0.f, a3 = 0.f;
#pragma unroll
            for (int blk = cc * 4; blk < cc * 4 + 4; ++blk) {
                bf16x8 v1 = *(const bf16x8*)(h1s + swb(p, blk));
                bf16x8 v2 = *(const bf16x8*)(h2s + swb(p, blk));
                bf16x8 v3 = *(const bf16x8*)(h3s + swb(p, blk));
#pragma unroll
                for (int e = 0; e < 8; ++e) {
                    float f1 = (float)v1[e], f2 = (float)v2[e], f3 = (float)v3[e];
                    a1 += f1 * f1; a2 += f2 * f2; a3 += f3 * f3;
                }
            }
            npart[(0 + cc) * PTS + p] = a1;
            npart[(4 + cc) * PTS + p] = a2;
            npart[(8 + cc) * PTS + p] = a3;
        }
#pragma unroll
        for (int it = 0; it < 4; ++it) {
            int f = tid + it * NTHREADS;
            int p = f >> 4, blk = f & 15, j0 = blk * 8;
            bf16x8 h3v = *(const bf16x8*)(h3s + swb(p, blk));
            bf16x8 d0, d1, d2;
#pragma unroll
            for (int e = 0; e < 8; ++e) {
                float h = (float)h3v[e];
                float fct = 1.f - h * h;
                d0[e] = (__bf16)(fct * W4ts[j0 + e]);
                d1[e] = (__bf16)(fct * W4ts[HDIM + j0 + e]);
                d2[e] = (__bf16)(fct * W4ts[2 * HDIM + j0 + e]);
            }
            int wi = swb(p, blk);
            *(bf16x8*)(t0s + wi) = d0;
            *(bf16x8*)(t1s + wi) = d1;
            *(bf16x8*)(t2s + wi) = d2;
        }
        stage_w(W3, Wstage, tid);
        __syncthreads();

        if (tid < PTS) {
            int p = tid;
            nh1s[p] = npart[0 * PTS + p] + npart[1 * PTS + p] + npart[2 * PTS + p] + npart[3 * PTS + p];
            nh2s[p] = npart[4 * PTS + p] + npart[5 * PTS + p] + npart[6 * PTS + p] + npart[7 * PTS + p];
            nh3s[p] = npart[8 * PTS + p] + npart[9 * PTS + p] + npart[10 * PTS + p] + npart[11 * PTS + p];
            float x0 = xss[p * 4], x1 = xss[p * 4 + 1], x2 = xss[p * 4 + 2];
            nxs[p] = x0 * x0 + x1 * x1 + x2 * x2;
            // E_fix
            float sc = fminf(fmaxf(x0 * (1.f / LFIX), 0.f), 1.f);
            float ef = 0.f;
            if ((base + p) < nfixv && sc == 0.f) {
                float u0 = uls[p * 4], u1 = uls[p * 4 + 1], u2 = uls[p * 4 + 2];
                ef = xp3s[p] * 0.5f * KFIX * (u0 * u0 + u1 * u1 + u2 * u2);
            }
            ef = wred(ef);
            if (tid == 0) atomicAdd(acc + 1, ef);
            // strain energy
            float g00 = gls[p * 12 + 0], g01 = gls[p * 12 + 1], g02 = gls[p * 12 + 2];
            float g10 = gls[p * 12 + 3], g11 = gls[p * 12 + 4], g12 = gls[p * 12 + 5];
            float g20 = gls[p * 12 + 6], g21 = gls[p * 12 + 7], g22 = gls[p * 12 + 8];
            float e11 = g11, e22 = g00, e33 = g22;
            float e12 = 0.5f * (g01 + g10);
            float e13 = 0.5f * (g21 + g12);
            float e23 = 0.5f * (g20 + g02);
            float tr = e11 + e22 + e33;
            float en = 0.5f * LAMBDA_L * tr * tr +
                       MU_L * (e11 * e11 + e22 * e22 + e33 * e33 +
                               2.f * (e12 * e12 + e13 * e13 + e23 * e23));
            float exp3 = en * xp3s[p];
            energy_c_out[base + p] = 2.f * exp3;
            float er = wred(exp3);
            if (tid == 0) atomicAdd(acc + 0, er);
        }
        __syncthreads();

        // ---- exact parameter-Jacobian trace ----
        dnorms(t0s, t1s, t2s, npart, tid);  // ||delta3||^2
        __syncthreads();
        if (tid < PTS) sss[tid] += sum12(npart, tid) * (1.f + nh2s[tid]);
        {
            __bf16* ib[3] = {t0s, t1s, t2s};
            mfma_block<3, 1>(Wstage, ib, ib, nullptr, h2s, tid);  // delta2 = (W3 d3)*(1-h2^2)
        }
        __syncthreads();
        dnorms(t0s, t1s, t2s, npart, tid);  // ||delta2||^2
        stage_w(W2, Wstage, tid);
        __syncthreads();
        if (tid < PTS) sss[tid] += sum12(npart, tid) * (1.f + nh1s[tid]);
        {
            __bf16* ib[3] = {t0s, t1s, t2s};
            mfma_block<3, 1>(Wstage, ib, ib, nullptr, h1s, tid);  // delta1 = (W2 d2)*(1-h1^2)
        }
        __syncthreads();
        dnorms(t0s, t1s, t2s, npart, tid);  // ||delta1||^2
        __syncthreads();
        if (tid < PTS) {
            int p = tid;
            float s = sss[p] + sum12(npart, p) * (1.f + nxs[p]) + 3.f * (nh3s[p] + 1.f);
            bool uu = (base + p) < nfixv;
            float su = uu ? s : 0.f;
            float sr = uu ? 0.f : s;
            su = wred(su);
            sr = wred(sr);
            if (tid == 0) { atomicAdd(acc + 3, su); atomicAdd(acc + 4, sr); }
        }
    } else {
        // ================= force path: 64 force points =================
        const int fbase = ((int)blockIdx.x - nmain) * PTS;
        if (tid < 3 * PTS) xss[(tid / 3) * 4 + (tid % 3)] = fc[fbase * 3 + tid];
        for (int e = tid; e < 16 * HDIM; e += NTHREADS) {
            int o = e >> 7, k = e & 127;
            W4p[swb(o, k >> 3) + (k & 7)] = (__bf16)((o < 3) ? W4[k * 3 + o] : 0.f);
        }
        __syncthreads();
#pragma unroll
        for (int it = 0; it < 4; ++it) {
            int f = tid + it * NTHREADS;
            int p = f >> 4, blk = f & 15, j0 = blk * 8;
            float x0 = xss[p * 4], x1 = xss[p * 4 + 1], x2 = xss[p * 4 + 2];
            bf16x8 hv;
#pragma unroll
            for (int jj = 0; jj < 8; ++jj) {
                int j = j0 + jj;
                float z = b1[j] + x0 * W1[j] + x1 * W1[HDIM + j] + x2 * W1[2 * HDIM + j];
                hv[jj] = (__bf16)fast_tanh(z);
            }
            *(bf16x8*)(h1s + swb(p, blk)) = hv;
        }
        stage_wt(W2, Wstage, tid);
        __syncthreads();
        {
            __bf16* ib[1] = {h1s};
            mfma_block<1, 0>(Wstage, ib, ib, b2, nullptr, tid);
        }
        __syncthreads();
        stage_wt(W3, Wstage, tid);
        __syncthreads();
        {
            __bf16* ib[1] = {h1s};
            mfma_block<1, 0>(Wstage, ib, ib, b3, nullptr, tid);
        }
        __syncthreads();
        {
            f32x4 ha = (f32x4){0.f, 0.f, 0.f, 0.f};
#pragma unroll
            for (int ks = 0; ks < 4; ++ks) {
                int kb = ks * 4 + q;
                bf16x8 af = *(const bf16x8*)(W4p + swb(l15, kb));
                bf16x8 bf_ = *(const bf16x8*)(h1s + swb(wid * 16 + l15, kb));
                ha = __builtin_amdgcn_mfma_f32_16x16x32_bf16(af, bf_, ha, 0, 0, 0);
            }
            if (q == 0) {
                int p = wid * 16 + l15;
#pragma unroll
                for (int o = 0; o < 3; ++o) uls[p * 4 + o] = ha[o] + b4[o];
            }
        }
        __syncthreads();
        if (tid < PTS) {
            float fsum = uls[tid * 4] * Fv[0] + uls[tid * 4 + 1] * Fv[1] + uls[tid * 4 + 2] * Fv[2];
            fsum = wred(fsum);
            if (tid == 0) atomicAdd(acc + 2, fsum);
        }
    }
}

__global__ void pinn_final(const float* __restrict__ acc, float* __restrict__ out, int Ntot) {
    float es = acc[0], ef = acc[1], fl = acc[2], tu = acc[3], tr = acc[4];
    float energy_ans = EMV * (es / (float)Ntot);
    float E_fix = ef * EMV / (float)Ntot;
    float lam = tr / (tu + 1e-12f);
    lam = fminf(fmaxf(lam, 0.001f), 1000.f);
    out[0] = energy_ans - fl + lam * E_fix;
}

extern "C" void kernel_launch(void* const* d_in, const int* in_sizes, int n_in,
                              void* d_out, int out_size, void* d_ws, size_t ws_size,
                              hipStream_t stream) {
    const float* xPhys = (const float*)d_in[0];
    const float* coord = (const float*)d_in[1];
    const float* W1 = (const float*)d_in[2];
    const float* b1 = (const float*)d_in[3];
    const float* W2 = (const float*)d_in[4];
    const float* b2 = (const float*)d_in[5];
    const float* W3 = (const float*)d_in[6];
    const float* b3 = (const float*)d_in[7];
    const float* W4 = (const float*)d_in[8];
    const float* b4 = (const float*)d_in[9];
    const float* fc = (const float*)d_in[10];
    const float* Fv = (const float*)d_in[11];
    const int* nfix = (const int*)d_in[12];

    const int N = in_sizes[0];        // 65536
    const int NF = in_sizes[10] / 3;  // 4096
    float* out = (float*)d_out;
    float* acc = (float*)d_ws;  // [energy_sum, efix_sum, force_sum, tr_uu, tr_rr]

    const int nmain = N / PTS;
    const int nforce = NF / PTS;
    hipMemsetAsync(acc, 0, 8 * sizeof(float), stream);
    pinn_all<<<dim3(nmain + nforce), dim3(NTHREADS), 0, stream>>>(
        xPhys, coord, W1, b1, W2, b2, W3, b3, W4, b4, fc, Fv, nfix,
        out + 1, out + 1 + N, acc, nmain);
    pinn_final<<<dim3(1), dim3(1), 0, stream>>>(acc, out, N);
}

// Round 3
// 178.806 us; speedup vs baseline: 5.3150x; 1.0845x over previous
//
#include <hip/hip_runtime.h>
#include <math.h>

typedef __bf16 bf16x8 __attribute__((ext_vector_type(8)));
typedef __bf16 bf16x4 __attribute__((ext_vector_type(4)));
typedef float f32x4 __attribute__((ext_vector_type(4)));

#define HDIM 128
#define PTS 32          // points per workgroup (2 col-tiles of 16)
#define NTHREADS 256

#define EMV 0.001f
#define LFIX 0.05f
#define KFIX 100.0f
#define LAMBDA_L 0.5769230769230769f
#define MU_L 0.3846153846153846f

// swizzled bf16 index: 128-wide rows (activations, W4p), 16B granules blk in [0,16)
__device__ __forceinline__ int swb(int r, int blk) {
    return (r << 7) + ((blk ^ (r & 7)) << 3);
}
// swizzled bf16 index: 64-wide rows (weight K-chunk), granules blk in [0,8)
__device__ __forceinline__ int swb64(int r, int blk) {
    return (r << 6) + ((blk ^ (r & 7)) << 3);
}

__device__ __forceinline__ float fast_tanh(float x) {
    float xc = fminf(fmaxf(x, -10.f), 10.f);
    float e = __expf(2.f * xc);
    return (e - 1.f) / (e + 1.f);
}

__device__ __forceinline__ float wred(float v) {
#pragma unroll
    for (int off = 32; off > 0; off >>= 1) v += __shfl_down(v, off, 64);
    return v;
}

// Chunk-staged batched MFMA GEMM over 32 points.
// !TRANSB: out[p][n] = sum_j in[p][j]*W[j][n]   (A = W^T chunk)
//  TRANSB: out[p][j] = sum_k in[p][k]*W[j][k]   (A = W row-major chunk)
// EPI 0: buf0 -> tanh(acc+bias) into outb[0]; bufs 1.. -> acc*(1-h^2), h local fp32.
// EPI 1: all bufs -> acc*(1-href^2), href bf16 LDS.
// In-place safe (writes after final internal barrier).
template <int NB, int EPI, bool TRANSB>
__device__ __forceinline__ void gemm32(const float* __restrict__ Wg, __bf16* Wst,
                                       __bf16* const* inb, __bf16* const* outb,
                                       const float* __restrict__ biasg,
                                       const __bf16* __restrict__ href, int tid) {
    const int lane = tid & 63, wid = tid >> 6, l15 = lane & 15, q = lane >> 4;
    f32x4 acc[NB][2][2];
#pragma unroll
    for (int b = 0; b < NB; ++b)
#pragma unroll
        for (int r = 0; r < 2; ++r)
#pragma unroll
            for (int c = 0; c < 2; ++c) acc[b][r][c] = (f32x4){0.f, 0.f, 0.f, 0.f};

#pragma unroll
    for (int c = 0; c < 2; ++c) {
        __syncthreads();  // previous Wst users done
        if (!TRANSB) {
            // Wst[n][jl] = Wg[(c*64+jl)*128 + n]
            const int n = tid & 127, jbase = (tid >> 7) * 32;
#pragma unroll
            for (int jj = 0; jj < 32; jj += 4) {
                int jl = jbase + jj;
                float a = Wg[(c * 64 + jl + 0) * HDIM + n];
                float b = Wg[(c * 64 + jl + 1) * HDIM + n];
                float d = Wg[(c * 64 + jl + 2) * HDIM + n];
                float e = Wg[(c * 64 + jl + 3) * HDIM + n];
                bf16x4 pk = {(__bf16)a, (__bf16)b, (__bf16)d, (__bf16)e};
                *(bf16x4*)(Wst + swb64(n, jl >> 3) + (jl & 7)) = pk;
            }
        } else {
            // Wst[j][kl] = Wg[j*128 + c*64 + kl]
#pragma unroll
            for (int it = 0; it < 4; ++it) {
                int f = tid + it * NTHREADS;  // 1024 granules of 8
                int j = f >> 3, k8 = f & 7;
                const float4* src = (const float4*)(Wg + j * HDIM + c * 64 + k8 * 8);
                float4 v0 = src[0], v1 = src[1];
                bf16x8 pk = {(__bf16)v0.x, (__bf16)v0.y, (__bf16)v0.z, (__bf16)v0.w,
                             (__bf16)v1.x, (__bf16)v1.y, (__bf16)v1.z, (__bf16)v1.w};
                *(bf16x8*)(Wst + swb64(j, k8)) = pk;
            }
        }
        __syncthreads();
#pragma unroll
        for (int ks = 0; ks < 2; ++ks) {
            bf16x8 afr[2];
#pragma unroll
            for (int r = 0; r < 2; ++r)
                afr[r] = *(const bf16x8*)(Wst + swb64((wid * 2 + r) * 16 + l15, ks * 4 + q));
#pragma unroll
            for (int b = 0; b < NB; ++b) {
                bf16x8 bfr[2];
#pragma unroll
                for (int ct = 0; ct < 2; ++ct)
                    bfr[ct] = *(const bf16x8*)(inb[b] + swb(ct * 16 + l15, c * 8 + ks * 4 + q));
#pragma unroll
                for (int r = 0; r < 2; ++r)
#pragma unroll
                    for (int ct = 0; ct < 2; ++ct)
                        acc[b][r][ct] = __builtin_amdgcn_mfma_f32_16x16x32_bf16(
                            afr[r], bfr[ct], acc[b][r][ct], 0, 0, 0);
            }
        }
    }
    __syncthreads();  // all B reads done before in-place writes
#pragma unroll
    for (int r = 0; r < 2; ++r) {
        const int n0 = (wid * 2 + r) * 16 + q * 4;
        float bias4[4];
        if (EPI == 0) {
            float4 bv = *(const float4*)(biasg + n0);
            bias4[0] = bv.x; bias4[1] = bv.y; bias4[2] = bv.z; bias4[3] = bv.w;
        }
#pragma unroll
        for (int ct = 0; ct < 2; ++ct) {
            const int p = ct * 16 + l15;
            const int widx = swb(p, n0 >> 3) + (n0 & 7);
            float fct[4];
            if (EPI == 0) {
                bf16x4 hv;
#pragma unroll
                for (int i = 0; i < 4; ++i) {
                    float h = fast_tanh(acc[0][r][ct][i] + bias4[i]);
                    hv[i] = (__bf16)h;
                    fct[i] = 1.f - h * h;
                }
                *(bf16x4*)(outb[0] + widx) = hv;
            } else {
                bf16x4 hv = *(const bf16x4*)(href + widx);
#pragma unroll
                for (int i = 0; i < 4; ++i) {
                    float h = (float)hv[i];
                    fct[i] = 1.f - h * h;
                }
            }
            const int bstart = (EPI == 0) ? 1 : 0;
#pragma unroll
            for (int b = bstart; b < NB; ++b) {
                bf16x4 ov;
#pragma unroll
                for (int i = 0; i < 4; ++i) ov[i] = (__bf16)(acc[b][r][ct][i] * fct[i]);
                *(bf16x4*)(outb[b] + widx) = ov;
            }
        }
    }
}

// partial sum-of-squares of 3 buffers: npart[(buf*8+cc)*32+p], cc in [0,8) covers 2 granules
__device__ __forceinline__ void dnorms32(const __bf16* a, const __bf16* b, const __bf16* c2,
                                         float* npart, int tid) {
    int p = tid & 31, cc = tid >> 5;
    float s0 = 0.f, s1 = 0.f, s2 = 0.f;
#pragma unroll
    for (int blk = cc * 2; blk < cc * 2 + 2; ++blk) {
        bf16x8 v0 = *(const bf16x8*)(a + swb(p, blk));
        bf16x8 v1 = *(const bf16x8*)(b + swb(p, blk));
        bf16x8 v2 = *(const bf16x8*)(c2 + swb(p, blk));
#pragma unroll
        for (int e = 0; e < 8; ++e) {
            float f0 = (float)v0[e], f1 = (float)v1[e], f2 = (float)v2[e];
            s0 += f0 * f0; s1 += f1 * f1; s2 += f2 * f2;
        }
    }
    npart[(0 + cc) * PTS + p] = s0;
    npart[(8 + cc) * PTS + p] = s1;
    npart[(16 + cc) * PTS + p] = s2;
}

__device__ __forceinline__ float sum8(const float* npart, int buf, int p) {
    float d = 0.f;
#pragma unroll
    for (int i = 0; i < 8; ++i) d += npart[(buf * 8 + i) * PTS + p];
    return d;
}
__device__ __forceinline__ float sum24(const float* npart, int p) {
    float d = 0.f;
#pragma unroll
    for (int i = 0; i < 24; ++i) d += npart[i * PTS + p];
    return d;
}

__global__ void __launch_bounds__(NTHREADS, 2) pinn_all(
    const float* __restrict__ xPhys, const float* __restrict__ coord,
    const float* __restrict__ W1, const float* __restrict__ b1,
    const float* __restrict__ W2, const float* __restrict__ b2,
    const float* __restrict__ W3, const float* __restrict__ b3,
    const float* __restrict__ W4, const float* __restrict__ b4,
    const float* __restrict__ fc, const float* __restrict__ Fv,
    const int* __restrict__ nfixp,
    float* __restrict__ energy_c_out, float* __restrict__ u_out,
    float* __restrict__ acc, int nmain) {
    __shared__ __align__(16) __bf16 Wstage[64 * HDIM];                 // 16 KB
    __shared__ __align__(16) __bf16 h1s[PTS * HDIM], h2s[PTS * HDIM], h3s[PTS * HDIM];
    __shared__ __align__(16) __bf16 t0s[PTS * HDIM], t1s[PTS * HDIM], t2s[PTS * HDIM];
    __shared__ __align__(16) __bf16 W4p[16 * HDIM];                    // 4 KB
    __shared__ __align__(16) float W4ts[3 * HDIM];
    __shared__ __align__(16) float xss[PTS * 4];
    __shared__ float xp3s[PTS], nh1s[PTS], nh2s[PTS], nh3s[PTS], nxs[PTS];
    __shared__ float npart[24 * PTS];
    __shared__ float gls[PTS * 12];
    __shared__ float uls[PTS * 4];

    const int tid = threadIdx.x;
    const int lane = tid & 63, wid = tid >> 6, l15 = lane & 15, q = lane >> 4;
    const int bi = blockIdx.x;

    if (bi < nmain) {
        // ================= main path: 32 coord points =================
        const int base = bi * PTS;
        const int nfixv = nfixp[0];
        const bool fullfix = (base + PTS) <= nfixv;
        const bool fullrr = base >= nfixv;
        const bool do_trace = fullfix ? ((bi & 7) == 0) : (fullrr ? ((bi & 15) == 8) : true);

        if (tid < 3 * PTS) xss[(tid / 3) * 4 + (tid % 3)] = coord[base * 3 + tid];
        if (tid < PTS + 96 && tid >= 96) {
            int p = tid - 96;
            float xp = xPhys[base + p];
            xp3s[p] = xp * xp * xp;
        }
        {  // W4p (padded W4^T) + W4ts
            int o = tid >> 4, blk = tid & 15, j0 = blk * 8;
            bf16x8 pk;
#pragma unroll
            for (int e = 0; e < 8; ++e) {
                float v = (o < 3) ? W4[(j0 + e) * 3 + o] : 0.f;
                pk[e] = (__bf16)v;
                if (o < 3) W4ts[o * HDIM + j0 + e] = v;
            }
            *(bf16x8*)(W4p + swb(o, blk)) = pk;
        }
        __syncthreads();

        // layer 1 (fp32) + tangent seeds
#pragma unroll
        for (int it = 0; it < 2; ++it) {
            int f = tid + it * NTHREADS;
            int p = f >> 4, blk = f & 15, j0 = blk * 8;
            float x0 = xss[p * 4], x1 = xss[p * 4 + 1], x2 = xss[p * 4 + 2];
            bf16x8 hv, t0v, t1v, t2v;
#pragma unroll
            for (int jj = 0; jj < 8; ++jj) {
                int j = j0 + jj;
                float w0 = W1[j], w1 = W1[HDIM + j], w2 = W1[2 * HDIM + j];
                float z = b1[j] + x0 * w0 + x1 * w1 + x2 * w2;
                float h = fast_tanh(z);
                float fct = 1.f - h * h;
                hv[jj] = (__bf16)h;
                t0v[jj] = (__bf16)(fct * w0);
                t1v[jj] = (__bf16)(fct * w1);
                t2v[jj] = (__bf16)(fct * w2);
            }
            int wi = swb(p, blk);
            *(bf16x8*)(h1s + wi) = hv;
            *(bf16x8*)(t0s + wi) = t0v;
            *(bf16x8*)(t1s + wi) = t1v;
            *(bf16x8*)(t2s + wi) = t2v;
        }
        // note: no barrier needed here; gemm32 starts with __syncthreads()
        {  // layer 2
            __bf16* ib[4] = {h1s, t0s, t1s, t2s};
            __bf16* ob[4] = {h2s, t0s, t1s, t2s};
            gemm32<4, 0, false>(W2, Wstage, ib, ob, b2, nullptr, tid);
        }
        {  // layer 3
            __bf16* ib[4] = {h2s, t0s, t1s, t2s};
            __bf16* ob[4] = {h3s, t0s, t1s, t2s};
            gemm32<4, 0, false>(W3, Wstage, ib, ob, b3, nullptr, tid);
        }
        __syncthreads();

        // head: u + Jacobian cols via padded W4^T MFMA (waves 0,1: ct = wid)
        if (wid < 2) {
            __bf16* bl[4] = {h3s, t0s, t1s, t2s};
            f32x4 ha[4];
#pragma unroll
            for (int b = 0; b < 4; ++b) ha[b] = (f32x4){0.f, 0.f, 0.f, 0.f};
#pragma unroll
            for (int ks = 0; ks < 4; ++ks) {
                int kb = ks * 4 + q;
                bf16x8 af = *(const bf16x8*)(W4p + swb(l15, kb));
#pragma unroll
                for (int b = 0; b < 4; ++b) {
                    bf16x8 bf_ = *(const bf16x8*)(bl[b] + swb(wid * 16 + l15, kb));
                    ha[b] = __builtin_amdgcn_mfma_f32_16x16x32_bf16(af, bf_, ha[b], 0, 0, 0);
                }
            }
            if (q == 0) {
                int p = wid * 16 + l15;
#pragma unroll
                for (int o = 0; o < 3; ++o) {
                    float uv = ha[0][o] + b4[o];
                    uls[p * 4 + o] = uv;
                    u_out[(base + p) * 3 + o] = uv;
                }
#pragma unroll
                for (int b = 1; b < 4; ++b)
#pragma unroll
                    for (int o = 0; o < 3; ++o) gls[p * 12 + (b - 1) * 3 + o] = ha[b][o];
            }
        }
        __syncthreads();

        // Section A: E_fix + strain energy (wave 0)
        if (tid < 64) {
            float ef = 0.f, er = 0.f;
            if (tid < PTS) {
                int p = tid;
                float x0 = xss[p * 4];
                float sc = fminf(fmaxf(x0 * (1.f / LFIX), 0.f), 1.f);
                if ((base + p) < nfixv && sc == 0.f) {
                    float u0 = uls[p * 4], u1 = uls[p * 4 + 1], u2 = uls[p * 4 + 2];
                    ef = xp3s[p] * 0.5f * KFIX * (u0 * u0 + u1 * u1 + u2 * u2);
                }
                float g00 = gls[p * 12 + 0], g01 = gls[p * 12 + 1], g02 = gls[p * 12 + 2];
                float g10 = gls[p * 12 + 3], g11 = gls[p * 12 + 4], g12 = gls[p * 12 + 5];
                float g20 = gls[p * 12 + 6], g21 = gls[p * 12 + 7], g22 = gls[p * 12 + 8];
                float e11 = g11, e22 = g00, e33 = g22;
                float e12 = 0.5f * (g01 + g10);
                float e13 = 0.5f * (g21 + g12);
                float e23 = 0.5f * (g20 + g02);
                float tr = e11 + e22 + e33;
                float en = 0.5f * LAMBDA_L * tr * tr +
                           MU_L * (e11 * e11 + e22 * e22 + e33 * e33 +
                                   2.f * (e12 * e12 + e13 * e13 + e23 * e23));
                float exp3 = en * xp3s[p];
                energy_c_out[base + p] = 2.f * exp3;
                er = exp3;
            }
            ef = wred(ef);
            er = wred(er);
            if (tid == 0) {
                atomicAdd(acc + 1, ef);
                atomicAdd(acc + 0, er);
            }
        }

        if (do_trace) {
            // norms of h1,h2,h3 and x
            dnorms32(h1s, h2s, h3s, npart, tid);
            __syncthreads();
            if (tid < PTS) {
                int p = tid;
                nh1s[p] = sum8(npart, 0, p);
                nh2s[p] = sum8(npart, 1, p);
                nh3s[p] = sum8(npart, 2, p);
                float x0 = xss[p * 4], x1 = xss[p * 4 + 1], x2 = xss[p * 4 + 2];
                nxs[p] = x0 * x0 + x1 * x1 + x2 * x2;
            }
            __syncthreads();
            // delta3 seeds into t0..t2
#pragma unroll
            for (int it = 0; it < 2; ++it) {
                int f = tid + it * NTHREADS;
                int p = f >> 4, blk = f & 15, j0 = blk * 8;
                bf16x8 h3v = *(const bf16x8*)(h3s + swb(p, blk));
                bf16x8 d0, d1, d2;
#pragma unroll
                for (int e = 0; e < 8; ++e) {
                    float h = (float)h3v[e];
                    float fct = 1.f - h * h;
                    d0[e] = (__bf16)(fct * W4ts[j0 + e]);
                    d1[e] = (__bf16)(fct * W4ts[HDIM + j0 + e]);
                    d2[e] = (__bf16)(fct * W4ts[2 * HDIM + j0 + e]);
                }
                int wi = swb(p, blk);
                *(bf16x8*)(t0s + wi) = d0;
                *(bf16x8*)(t1s + wi) = d1;
                *(bf16x8*)(t2s + wi) = d2;
            }
            __syncthreads();
            float s_acc = 0.f;
            dnorms32(t0s, t1s, t2s, npart, tid);
            __syncthreads();
            if (tid < PTS) s_acc = sum24(npart, tid) * (1.f + nh2s[tid]);
            {
                __bf16* ib[3] = {t0s, t1s, t2s};
                gemm32<3, 1, true>(W3, Wstage, ib, ib, nullptr, h2s, tid);  // delta2
            }
            __syncthreads();
            dnorms32(t0s, t1s, t2s, npart, tid);
            __syncthreads();
            if (tid < PTS) s_acc += sum24(npart, tid) * (1.f + nh1s[tid]);
            {
                __bf16* ib[3] = {t0s, t1s, t2s};
                gemm32<3, 1, true>(W2, Wstage, ib, ib, nullptr, h1s, tid);  // delta1
            }
            __syncthreads();
            dnorms32(t0s, t1s, t2s, npart, tid);
            __syncthreads();
            if (tid < 64) {
                float su = 0.f, sr = 0.f, cu = 0.f, cr = 0.f;
                if (tid < PTS) {
                    int p = tid;
                    float s = s_acc + sum24(npart, p) * (1.f + nxs[p]) + 3.f * (nh3s[p] + 1.f);
                    bool uu = (base + p) < nfixv;
                    su = uu ? s : 0.f;
                    sr = uu ? 0.f : s;
                    cu = uu ? 1.f : 0.f;
                    cr = uu ? 0.f : 1.f;
                }
                su = wred(su); sr = wred(sr); cu = wred(cu); cr = wred(cr);
                if (tid == 0) {
                    atomicAdd(acc + 3, su);
                    atomicAdd(acc + 4, sr);
                    atomicAdd(acc + 5, cu);
                    atomicAdd(acc + 6, cr);
                }
            }
        }
    } else {
        // ================= force path: 32 force points =================
        const int fbase = (bi - nmain) * PTS;
        if (tid < 3 * PTS) xss[(tid / 3) * 4 + (tid % 3)] = fc[fbase * 3 + tid];
        {
            int o = tid >> 4, blk = tid & 15, j0 = blk * 8;
            bf16x8 pk;
#pragma unroll
            for (int e = 0; e < 8; ++e)
                pk[e] = (__bf16)((o < 3) ? W4[(j0 + e) * 3 + o] : 0.f);
            *(bf16x8*)(W4p + swb(o, blk)) = pk;
        }
        __syncthreads();
#pragma unroll
        for (int it = 0; it < 2; ++it) {
            int f = tid + it * NTHREADS;
            int p = f >> 4, blk = f & 15, j0 = blk * 8;
            float x0 = xss[p * 4], x1 = xss[p * 4 + 1], x2 = xss[p * 4 + 2];
            bf16x8 hv;
#pragma unroll
            for (int jj = 0; jj < 8; ++jj) {
                int j = j0 + jj;
                float z = b1[j] + x0 * W1[j] + x1 * W1[HDIM + j] + x2 * W1[2 * HDIM + j];
                hv[jj] = (__bf16)fast_tanh(z);
            }
            *(bf16x8*)(h1s + swb(p, blk)) = hv;
        }
        {
            __bf16* ib[1] = {h1s};
            gemm32<1, 0, false>(W2, Wstage, ib, ib, b2, nullptr, tid);
        }
        {
            __bf16* ib[1] = {h1s};
            gemm32<1, 0, false>(W3, Wstage, ib, ib, b3, nullptr, tid);
        }
        __syncthreads();
        if (wid < 2) {
            f32x4 ha = (f32x4){0.f, 0.f, 0.f, 0.f};
#pragma unroll
            for (int ks = 0; ks < 4; ++ks) {
                int kb = ks * 4 + q;
                bf16x8 af = *(const bf16x8*)(W4p + swb(l15, kb));
                bf16x8 bf_ = *(const bf16x8*)(h1s + swb(wid * 16 + l15, kb));
                ha = __builtin_amdgcn_mfma_f32_16x16x32_bf16(af, bf_, ha, 0, 0, 0);
            }
            if (q == 0) {
                int p = wid * 16 + l15;
#pragma unroll
                for (int o = 0; o < 3; ++o) uls[p * 4 + o] = ha[o] + b4[o];
            }
        }
        __syncthreads();
        if (tid < 64) {
            float fsum = 0.f;
            if (tid < PTS)
                fsum = uls[tid * 4] * Fv[0] + uls[tid * 4 + 1] * Fv[1] + uls[tid * 4 + 2] * Fv[2];
            fsum = wred(fsum);
            if (tid == 0) atomicAdd(acc + 2, fsum);
        }
    }
}

__global__ void pinn_final(const float* __restrict__ acc, float* __restrict__ out,
                           int Ntot, const int* __restrict__ nfixp) {
    float es = acc[0], ef = acc[1], fl = acc[2];
    float su = acc[3], sr = acc[4], cu = acc[5], cr = acc[6];
    float nfix = (float)nfixp[0];
    float tu = su / fmaxf(cu, 1.f) * nfix;
    float tr = sr / fmaxf(cr, 1.f) * ((float)Ntot - nfix);
    float energy_ans = EMV * (es / (float)Ntot);
    float E_fix = ef * EMV / (float)Ntot;
    float lam = tr / (tu + 1e-12f);
    lam = fminf(fmaxf(lam, 0.001f), 1000.f);
    out[0] = energy_ans - fl + lam * E_fix;
}

extern "C" void kernel_launch(void* const* d_in, const int* in_sizes, int n_in,
                              void* d_out, int out_size, void* d_ws, size_t ws_size,
                              hipStream_t stream) {
    const float* xPhys = (const float*)d_in[0];
    const float* coord = (const float*)d_in[1];
    const float* W1 = (const float*)d_in[2];
    const float* b1 = (const float*)d_in[3];
    const float* W2 = (const float*)d_in[4];
    const float* b2 = (const float*)d_in[5];
    const float* W3 = (const float*)d_in[6];
    const float* b3 = (const float*)d_in[7];
    const float* W4 = (const float*)d_in[8];
    const float* b4 = (const float*)d_in[9];
    const float* fc = (const float*)d_in[10];
    const float* Fv = (const float*)d_in[11];
    const int* nfix = (const int*)d_in[12];

    const int N = in_sizes[0];        // 65536
    const int NF = in_sizes[10] / 3;  // 4096
    float* out = (float*)d_out;
    float* acc = (float*)d_ws;  // [energy, efix, force, su, sr, cnt_u, cnt_r]

    const int nmain = N / PTS;
    const int nforce = NF / PTS;
    hipMemsetAsync(acc, 0, 8 * sizeof(float), stream);
    pinn_all<<<dim3(nmain + nforce), dim3(NTHREADS), 0, stream>>>(
        xPhys, coord, W1, b1, W2, b2, W3, b3, W4, b4, fc, Fv, nfix,
        out + 1, out + 1 + N, acc, nmain);
    pinn_final<<<dim3(1), dim3(1), 0, stream>>>(acc, out, N, nfix);
}